// Round 8
// baseline (46.907 us; speedup 1.0000x reference)
//
#include <hip/hip_runtime.h>
#include <hip/hip_bf16.h>
#include <math.h>

typedef __bf16 bf16x4 __attribute__((ext_vector_type(4)));
typedef __bf16 bf16x8 __attribute__((ext_vector_type(8)));
typedef float  f32x4  __attribute__((ext_vector_type(4)));

#define HW 16384   // 128*128
#define CCH 64
#define OCH 64

__device__ static const float FIRTAB[62] = {
  // db4 (8)
  -0.0105974017850021f, 0.0328830116668852f, 0.0308413818355607f, -0.1870348117188811f,
  -0.0279837694169839f, 0.6308807679295904f, 0.7148465705529155f, 0.2303778133088964f,
  // db6 (12)
  0.00107730108499558f, -0.00477725751101065f, -0.0005538422009938f, 0.03158203931748603f,
  0.02752286553030533f, -0.0975016055873225f, -0.12976686756709563f, 0.22626469396544f,
  0.3152503517092432f, -0.7511339080210959f, 0.4946238903984534f, 0.1115407433501095f,
  // sym6 (12)
  -0.007800708325034148f, 0.001767711864242804f, 0.04472490177066578f, -0.02106029251230056f,
  -0.0726375227866f, 0.3379294217282401f, 0.787641141030194f, 0.4910559419267466f,
  -0.048311742585632f, -0.1179901111484105f, 0.00349071208421747f, 0.01540410932702737f,
  // coif5 (30)
  -3.459977283621256e-05f, -7.098330313814114e-05f, 0.0004662169601128863f, 0.001117518770890601f,
  -0.002574517688750223f, -0.00900797613666158f, 0.015880544863615904f, 0.03455502757306163f,
  -0.08230192710688598f, -0.07179982161931202f, 0.42848347637761874f, 0.7937772226256206f,
  0.4051769024096169f, -0.06112339000267287f, -0.06577191128185562f, 0.023452696141836267f,
  0.007782596427325418f, -0.003793512864491014f, -0.0002606761356811993f, 0.000107502882505652f,
  1.10319778524429e-05f, -5.520763127949e-06f, -1.0682196848076e-06f, 5.236425333584e-07f,
  1.125098976034e-07f, -5.417490769329e-08f, -8.8631e-09f, 4.2921e-09f, 6.7e-10f, -3.2e-10f
};
__device__ static const int FIR_OFF[4] = {0, 8, 20, 32};
__device__ static const int FIR_LEN[4] = {8, 12, 12, 30};

// ---------------------------------------------------------------------------
// Kernel 1 (proven, unchanged): build P_k (64x64), fragment-linear bf16 out.
//   entry (k, o, c) -> Pout[(((s*4+mf)*64 + lane)*8 + e]
//   s = 2k + (c>>5), mf = o>>4, lane = (o&15) | (((c&31)>>3)<<4), e = c&7
// ---------------------------------------------------------------------------
__global__ __launch_bounds__(256) void setup_P(
    const float* __restrict__ pw,
    const float* __restrict__ s53A, const float* __restrict__ s53D,
    const float* __restrict__ s97A, const float* __restrict__ s97D,
    __bf16* __restrict__ Pout)
{
  __shared__ float matA[64][64];
  __shared__ float matD[64][64];
  __shared__ float tmpA[62][64];
  __shared__ float tmpD[62][64];

  const int k = blockIdx.x >> 3;
  const int q = blockIdx.x & 7;
  const int t = threadIdx.x;

  if (t < 64) {
    const int c = t;
    int Lin;
    if (k < 4) {
      const int L  = FIR_LEN[k];
      const int off = FIR_OFF[k];
      const int pad = (L - 1) / 2;
      const int pl  = pad - 1;
      float ss = 0.f;
      for (int l = 0; l < L; ++l) { float v = FIRTAB[off + l]; ss += v * v; }
      const float inv = 1.f / (sqrtf(ss) + 1e-12f);

      for (int i = 0; i < 62; ++i) { tmpA[i][c] = 0.f; tmpD[i][c] = 0.f; }
      for (int l = 0; l < L; ++l) {
        const float lov = FIRTAB[off + l] * inv;
        const float hiv = ((l & 1) ? -1.f : 1.f) * FIRTAB[off + L - 1 - l] * inv;
        const int base = pl - l;
        int i0 = c + base;
        if (i0 >= 0 && i0 < 62) { tmpA[i0][c] += lov; tmpD[i0][c] += hiv; }
        if (c > 0) {
          int i1 = -c + base;
          if (i1 >= 0 && i1 < 62) { tmpA[i1][c] += lov; tmpD[i1][c] += hiv; }
        }
        if (c < 63) {
          int i2 = 126 - c + base;
          if (i2 >= 0 && i2 < 62) { tmpA[i2][c] += lov; tmpD[i2][c] += hiv; }
        }
      }
      Lin = 62;
    } else {
      for (int i = 0; i < 32; ++i) {
        tmpA[i][c] = (c == 2 * i)     ? 1.f : 0.f;
        tmpD[i][c] = (c == 2 * i + 1) ? 1.f : 0.f;
      }
      float cf[4]; int nst;
      if (k == 4) { cf[0] = -0.5f; cf[1] = 0.25f; cf[2] = 0.f; cf[3] = 0.f; nst = 2; }
      else { cf[0] = -1.586134342f; cf[1] = -0.05298011854f;
             cf[2] = 0.8829110762f; cf[3] = 0.4435068522f; nst = 4; }
      for (int s = 0; s < nst; ++s) {
        if ((s & 1) == 0) {
          for (int i = 0; i < 32; ++i) {
            float a = tmpA[(i == 0) ? 1 : i - 1][c];
            float b2 = tmpA[(i == 31) ? 30 : i + 1][c];
            tmpD[i][c] += cf[s] * 0.5f * (a + b2);
          }
        } else {
          for (int i = 0; i < 32; ++i) {
            float a = tmpD[(i == 0) ? 1 : i - 1][c];
            float b2 = tmpD[(i == 31) ? 30 : i + 1][c];
            tmpA[i][c] += cf[s] * 0.5f * (a + b2);
          }
        }
      }
      Lin = 32;
    }
    float sA = 1.f, sD = 1.f;
    if (k == 4) { sA = s53A[0]; sD = s53D[0]; }
    if (k == 5) { sA = s97A[0]; sD = s97D[0]; }
    const float step = (float)Lin / 64.0f;
    for (int o = 0; o < 64; ++o) {
      float src = (o + 0.5f) * step - 0.5f;
      src = fmaxf(src, 0.f);
      int i0 = (int)floorf(src); if (i0 > Lin - 1) i0 = Lin - 1;
      int i1 = i0 + 1;           if (i1 > Lin - 1) i1 = Lin - 1;
      float w = src - (float)i0;
      matA[o][c] = sA * ((1.f - w) * tmpA[i0][c] + w * tmpA[i1][c]);
      matD[o][c] = sD * ((1.f - w) * tmpD[i0][c] + w * tmpD[i1][c]);
    }
  }
  __syncthreads();

  const int o  = q * 8 + (t & 7);
  const int c0 = (t >> 3) * 2;
  float acc[2] = {0.f, 0.f};
  for (int j = 0; j < 64; ++j) {
    const float wa = pw[o * 128 + j];
    const float wd = pw[o * 128 + 64 + j];
    #pragma unroll
    for (int cc = 0; cc < 2; ++cc)
      acc[cc] += wa * matA[j][c0 + cc] + wd * matD[j][c0 + cc];
  }
  #pragma unroll
  for (int cc = 0; cc < 2; ++cc) {
    const int c = c0 + cc;
    const int s = k * 2 + (c >> 5);
    const int mf = o >> 4;
    const int lane = (o & 15) | (((c & 31) >> 3) << 4);
    const int e = c & 7;
    Pout[(((s * 4 + mf) * 64 + lane) << 3) + e] = (__bf16)acc[cc];
  }
}

// ---------------------------------------------------------------------------
// Kernel 2: barrier-free, LDS-free main kernel.
//  2048 blocks x 256 threads; 64 px per block; 4 independent waves.
//  Each lane loads its MFMA B-fragment DIRECTLY from global x (16 scalar f32
//  loads per pixel-group; lanes lr=0..15 hit consecutive pixels -> 4x64B
//  segments/instr; adjacent 64B consumed by the same wave's other pgs; the
//  4 waves share one XCD L2 so HBM fetch stays ~x-size).
//  Per pg: cvt->bf16, gate (2 MFMA + shfl butterfly + fast softmax, all in
//  regs), 12 weighted MFMA, 4 dword stores. Rolling 2-deep pg prefetch.
//  No __syncthreads anywhere -> every wave is an independent latency stream.
// ---------------------------------------------------------------------------
__global__ __launch_bounds__(256, 4) void wavelet_main(
    const float* __restrict__ xg,
    const float* __restrict__ gw1, const float* __restrict__ gb1,
    const float* __restrict__ gw2, const float* __restrict__ gb2,
    const float* __restrict__ pbias,
    const __bf16* __restrict__ Pws,
    float* __restrict__ outg)
{
  const int t    = threadIdx.x;
  const int w    = t >> 6;
  const int lane = t & 63;
  const int lr   = lane & 15;
  const int kq   = lane >> 4;

  const int tile  = blockIdx.x;
  const int b     = tile >> 8;                 // 256 tiles per image
  const int pbase = (tile & 255) << 6;         // 64 px per tile

  const float* xb = xg + (size_t)b * (CCH * HW) + pbase + lr;

  // ---- B prefetch: two rolling register sets, pg0 + pg1 issued up front ----
  float f0[2][16];
  #pragma unroll
  for (int s = 0; s < 2; ++s) {
    const float* bp = xb + s * 16;
    #pragma unroll
    for (int e = 0; e < 8; ++e) f0[s][e]     = bp[(size_t)(kq * 8 + e) * HW];
    #pragma unroll
    for (int e = 0; e < 8; ++e) f0[s][8 + e] = bp[(size_t)(32 + kq * 8 + e) * HW];
  }

  // ---- per-wave constants (L2-hot; latency hidden under B loads) ----
  bf16x8 A[12];
  #pragma unroll
  for (int kk = 0; kk < 6; ++kk)
    #pragma unroll
    for (int sh = 0; sh < 2; ++sh)
      A[kk * 2 + sh] = *(const bf16x8*)(Pws + (size_t)((((2 * kk + sh) * 4 + w) * 64 + lane) << 3));

  bf16x8 W1a[2];
  {
    const float* wp = gw1 + lr * 64 + kq * 8;
    #pragma unroll
    for (int hh = 0; hh < 2; ++hh) {
      f32x4 lo = *(const f32x4*)(wp + hh * 32);
      f32x4 hi = *(const f32x4*)(wp + hh * 32 + 4);
      bf16x8 a;
      #pragma unroll
      for (int e = 0; e < 4; ++e) { a[e] = (__bf16)lo[e]; a[e + 4] = (__bf16)hi[e]; }
      W1a[hh] = a;
    }
  }
  const f32x4 gb1v  = *(const f32x4*)(gb1 + kq * 4);
  const f32x4 biasv = *(const f32x4*)(pbias + w * 16 + kq * 4);

  float* outb = outg + (size_t)b * (OCH * HW) + pbase;

  #pragma unroll
  for (int pg = 0; pg < 4; ++pg) {
    float* cur = f0[pg & 1];

    // convert current pg to bf16 fragments (forces the wait on these 16 loads)
    bf16x8 B0, B1;
    #pragma unroll
    for (int e = 0; e < 8; ++e) { B0[e] = (__bf16)cur[e]; B1[e] = (__bf16)cur[8 + e]; }

    // rolling prefetch: pg+2 reuses this register set (WAR dep keeps order)
    if (pg + 2 < 4) {
      const float* bp = xb + (pg + 2) * 16;
      #pragma unroll
      for (int e = 0; e < 8; ++e) cur[e]     = bp[(size_t)(kq * 8 + e) * HW];
      #pragma unroll
      for (int e = 0; e < 8; ++e) cur[8 + e] = bp[(size_t)(32 + kq * 8 + e) * HW];
    }

    // ---- gate: h = relu(W1@x + b1) via MFMA; logits via shfl butterfly ----
    f32x4 h = {0.f, 0.f, 0.f, 0.f};
    h = __builtin_amdgcn_mfma_f32_16x16x32_bf16(W1a[0], B0, h, 0, 0, 0);
    h = __builtin_amdgcn_mfma_f32_16x16x32_bf16(W1a[1], B1, h, 0, 0, 0);
    float hr[4];
    #pragma unroll
    for (int j = 0; j < 4; ++j) hr[j] = fmaxf(h[j] + gb1v[j], 0.f);

    float lg[6];
    #pragma unroll
    for (int kk = 0; kk < 6; ++kk) {
      const f32x4 w2 = *(const f32x4*)(gw2 + kk * 16 + kq * 4);
      lg[kk] = w2[0] * hr[0] + w2[1] * hr[1] + w2[2] * hr[2] + w2[3] * hr[3];
    }
    #pragma unroll
    for (int kk = 0; kk < 6; ++kk) lg[kk] += __shfl_xor(lg[kk], 16);
    #pragma unroll
    for (int kk = 0; kk < 6; ++kk) lg[kk] += __shfl_xor(lg[kk], 32);
    #pragma unroll
    for (int kk = 0; kk < 6; ++kk) lg[kk] += gb2[kk];

    float mx = fmaxf(fmaxf(fmaxf(lg[0], lg[1]), fmaxf(lg[2], lg[3])), fmaxf(lg[4], lg[5]));
    float ex[6], ssum = 0.f;
    #pragma unroll
    for (int kk = 0; kk < 6; ++kk) { ex[kk] = __expf(lg[kk] - mx); ssum += ex[kk]; }
    const float sinv = __builtin_amdgcn_rcpf(ssum);
    float g6[6], wsum = 0.f;
    #pragma unroll
    for (int kk = 0; kk < 6; ++kk) { g6[kk] = ex[kk] * sinv; wsum += g6[kk]; }
    const float winv = __builtin_amdgcn_rcpf(wsum + 1e-12f);
    float wmv[6];
    #pragma unroll
    for (int kk = 0; kk < 6; ++kk) wmv[kk] = g6[kk] * winv;

    // ---- main: 6 weighted P_k @ x products ----
    f32x4 facc = biasv;
    #pragma unroll
    for (int kk = 0; kk < 6; ++kk) {
      f32x4 y = {0.f, 0.f, 0.f, 0.f};
      y = __builtin_amdgcn_mfma_f32_16x16x32_bf16(A[2 * kk    ], B0, y, 0, 0, 0);
      y = __builtin_amdgcn_mfma_f32_16x16x32_bf16(A[2 * kk + 1], B1, y, 0, 0, 0);
      #pragma unroll
      for (int j = 0; j < 4; ++j) facc[j] += wmv[kk] * y[j];
    }

    const int col = pg * 16 + lr;
    #pragma unroll
    for (int j = 0; j < 4; ++j) {
      const int o = w * 16 + kq * 4 + j;
      outb[(size_t)o * HW + col] = facc[j];
    }
  }
}

extern "C" void kernel_launch(void* const* d_in, const int* in_sizes, int n_in,
                              void* d_out, int out_size, void* d_ws, size_t ws_size,
                              hipStream_t stream) {
  const float* x    = (const float*)d_in[0];
  const float* gw1  = (const float*)d_in[1];
  const float* gb1  = (const float*)d_in[2];
  const float* gw2  = (const float*)d_in[3];
  const float* gb2  = (const float*)d_in[4];
  const float* pw   = (const float*)d_in[5];
  const float* pb   = (const float*)d_in[6];
  const float* s53A = (const float*)d_in[7];
  const float* s53D = (const float*)d_in[8];
  const float* s97A = (const float*)d_in[9];
  const float* s97D = (const float*)d_in[10];
  __bf16* Pws = (__bf16*)d_ws;
  float* out = (float*)d_out;

  setup_P<<<48, 256, 0, stream>>>(pw, s53A, s53D, s97A, s97D, Pws);
  wavelet_main<<<2048, 256, 0, stream>>>(x, gw1, gb1, gw2, gb2, pb, Pws, out);
}

// Round 9
// 38.978 us; speedup vs baseline: 1.2034x; 1.2034x over previous
//
#include <hip/hip_runtime.h>
#include <hip/hip_bf16.h>
#include <math.h>

typedef __bf16 bf16x4 __attribute__((ext_vector_type(4)));
typedef __bf16 bf16x8 __attribute__((ext_vector_type(8)));
typedef float  f32x4  __attribute__((ext_vector_type(4)));

#define HW 16384   // 128*128
#define CCH 64
#define OCH 64
#define OSTR 68    // obuf row stride in f32 (64 + 4 pad -> bank-spread)

__device__ static const float FIRTAB[62] = {
  // db4 (8)
  -0.0105974017850021f, 0.0328830116668852f, 0.0308413818355607f, -0.1870348117188811f,
  -0.0279837694169839f, 0.6308807679295904f, 0.7148465705529155f, 0.2303778133088964f,
  // db6 (12)
  0.00107730108499558f, -0.00477725751101065f, -0.0005538422009938f, 0.03158203931748603f,
  0.02752286553030533f, -0.0975016055873225f, -0.12976686756709563f, 0.22626469396544f,
  0.3152503517092432f, -0.7511339080210959f, 0.4946238903984534f, 0.1115407433501095f,
  // sym6 (12)
  -0.007800708325034148f, 0.001767711864242804f, 0.04472490177066578f, -0.02106029251230056f,
  -0.0726375227866f, 0.3379294217282401f, 0.787641141030194f, 0.4910559419267466f,
  -0.048311742585632f, -0.1179901111484105f, 0.00349071208421747f, 0.01540410932702737f,
  // coif5 (30)
  -3.459977283621256e-05f, -7.098330313814114e-05f, 0.0004662169601128863f, 0.001117518770890601f,
  -0.002574517688750223f, -0.00900797613666158f, 0.015880544863615904f, 0.03455502757306163f,
  -0.08230192710688598f, -0.07179982161931202f, 0.42848347637761874f, 0.7937772226256206f,
  0.4051769024096169f, -0.06112339000267287f, -0.06577191128185562f, 0.023452696141836267f,
  0.007782596427325418f, -0.003793512864491014f, -0.0002606761356811993f, 0.000107502882505652f,
  1.10319778524429e-05f, -5.520763127949e-06f, -1.0682196848076e-06f, 5.236425333584e-07f,
  1.125098976034e-07f, -5.417490769329e-08f, -8.8631e-09f, 4.2921e-09f, 6.7e-10f, -3.2e-10f
};
__device__ static const int FIR_OFF[4] = {0, 8, 20, 32};
__device__ static const int FIR_LEN[4] = {8, 12, 12, 30};

// ---------------------------------------------------------------------------
// Kernel 1 (proven, unchanged): build P_k (64x64), fragment-linear bf16 out.
//   entry (k, o, c) -> Pout[(((s*4+mf)*64 + lane)*8 + e]
//   s = 2k + (c>>5), mf = o>>4, lane = (o&15) | (((c&31)>>3)<<4), e = c&7
// ---------------------------------------------------------------------------
__global__ __launch_bounds__(256) void setup_P(
    const float* __restrict__ pw,
    const float* __restrict__ s53A, const float* __restrict__ s53D,
    const float* __restrict__ s97A, const float* __restrict__ s97D,
    __bf16* __restrict__ Pout)
{
  __shared__ float matA[64][64];
  __shared__ float matD[64][64];
  __shared__ float tmpA[62][64];
  __shared__ float tmpD[62][64];

  const int k = blockIdx.x >> 3;
  const int q = blockIdx.x & 7;
  const int t = threadIdx.x;

  if (t < 64) {
    const int c = t;
    int Lin;
    if (k < 4) {
      const int L  = FIR_LEN[k];
      const int off = FIR_OFF[k];
      const int pad = (L - 1) / 2;
      const int pl  = pad - 1;
      float ss = 0.f;
      for (int l = 0; l < L; ++l) { float v = FIRTAB[off + l]; ss += v * v; }
      const float inv = 1.f / (sqrtf(ss) + 1e-12f);

      for (int i = 0; i < 62; ++i) { tmpA[i][c] = 0.f; tmpD[i][c] = 0.f; }
      for (int l = 0; l < L; ++l) {
        const float lov = FIRTAB[off + l] * inv;
        const float hiv = ((l & 1) ? -1.f : 1.f) * FIRTAB[off + L - 1 - l] * inv;
        const int base = pl - l;
        int i0 = c + base;
        if (i0 >= 0 && i0 < 62) { tmpA[i0][c] += lov; tmpD[i0][c] += hiv; }
        if (c > 0) {
          int i1 = -c + base;
          if (i1 >= 0 && i1 < 62) { tmpA[i1][c] += lov; tmpD[i1][c] += hiv; }
        }
        if (c < 63) {
          int i2 = 126 - c + base;
          if (i2 >= 0 && i2 < 62) { tmpA[i2][c] += lov; tmpD[i2][c] += hiv; }
        }
      }
      Lin = 62;
    } else {
      for (int i = 0; i < 32; ++i) {
        tmpA[i][c] = (c == 2 * i)     ? 1.f : 0.f;
        tmpD[i][c] = (c == 2 * i + 1) ? 1.f : 0.f;
      }
      float cf[4]; int nst;
      if (k == 4) { cf[0] = -0.5f; cf[1] = 0.25f; cf[2] = 0.f; cf[3] = 0.f; nst = 2; }
      else { cf[0] = -1.586134342f; cf[1] = -0.05298011854f;
             cf[2] = 0.8829110762f; cf[3] = 0.4435068522f; nst = 4; }
      for (int s = 0; s < nst; ++s) {
        if ((s & 1) == 0) {
          for (int i = 0; i < 32; ++i) {
            float a = tmpA[(i == 0) ? 1 : i - 1][c];
            float b2 = tmpA[(i == 31) ? 30 : i + 1][c];
            tmpD[i][c] += cf[s] * 0.5f * (a + b2);
          }
        } else {
          for (int i = 0; i < 32; ++i) {
            float a = tmpD[(i == 0) ? 1 : i - 1][c];
            float b2 = tmpD[(i == 31) ? 30 : i + 1][c];
            tmpA[i][c] += cf[s] * 0.5f * (a + b2);
          }
        }
      }
      Lin = 32;
    }
    float sA = 1.f, sD = 1.f;
    if (k == 4) { sA = s53A[0]; sD = s53D[0]; }
    if (k == 5) { sA = s97A[0]; sD = s97D[0]; }
    const float step = (float)Lin / 64.0f;
    for (int o = 0; o < 64; ++o) {
      float src = (o + 0.5f) * step - 0.5f;
      src = fmaxf(src, 0.f);
      int i0 = (int)floorf(src); if (i0 > Lin - 1) i0 = Lin - 1;
      int i1 = i0 + 1;           if (i1 > Lin - 1) i1 = Lin - 1;
      float w = src - (float)i0;
      matA[o][c] = sA * ((1.f - w) * tmpA[i0][c] + w * tmpA[i1][c]);
      matD[o][c] = sD * ((1.f - w) * tmpD[i0][c] + w * tmpD[i1][c]);
    }
  }
  __syncthreads();

  const int o  = q * 8 + (t & 7);
  const int c0 = (t >> 3) * 2;
  float acc[2] = {0.f, 0.f};
  for (int j = 0; j < 64; ++j) {
    const float wa = pw[o * 128 + j];
    const float wd = pw[o * 128 + 64 + j];
    #pragma unroll
    for (int cc = 0; cc < 2; ++cc)
      acc[cc] += wa * matA[j][c0 + cc] + wd * matD[j][c0 + cc];
  }
  #pragma unroll
  for (int cc = 0; cc < 2; ++cc) {
    const int c = c0 + cc;
    const int s = k * 2 + (c >> 5);
    const int mf = o >> 4;
    const int lane = (o & 15) | (((c & 31) >> 3) << 4);
    const int e = c & 7;
    Pout[(((s * 4 + mf) * 64 + lane) << 3) + e] = (__bf16)acc[cc];
  }
}

// ---------------------------------------------------------------------------
// Kernel 2: R6 structure + coalesced-store epilogue (the ONE change).
//  2048 blocks x 256 threads; 64 px per block.
//  Phase 0: stage x (4 coalesced f32x4/thread) -> swizzled bf16 LDS tile.
//  Phase A: wave w gates its pixel-group; wm shared via LDS (R6, proven).
//  Phase B: per pg: 2 ds_read_b128 + 14 MFMA + weighted accumulate; facc
//           written to obuf LDS (stride-68 rows, ~2-way max) instead of 16
//           scattered 64B-segment global stores.
//  Epilogue: barrier, then 4x global_store_dwordx4 per wave — 4x256B
//           contiguous segments per instr (was 64x64B segments per wave).
// ---------------------------------------------------------------------------
__global__ __launch_bounds__(256, 4) void wavelet_main(
    const float* __restrict__ xg,
    const float* __restrict__ gw1, const float* __restrict__ gb1,
    const float* __restrict__ gw2, const float* __restrict__ gb2,
    const float* __restrict__ pbias,
    const __bf16* __restrict__ Pws,
    float* __restrict__ outg)
{
  __shared__ __align__(16) unsigned char xt[64 * 128];   //  8 KB
  __shared__ __align__(16) float wmld[64 * 8];           //  2 KB
  __shared__ __align__(16) float obuf[64 * OSTR];        // 17 KB

  const int t    = threadIdx.x;
  const int blk  = blockIdx.x;
  const int b    = blk >> 8;                 // 256 tiles per image
  const int pbase = (blk & 255) << 6;        // 64 px per tile
  const int w    = t >> 6;
  const int lane = t & 63;
  const int lr   = lane & 15;
  const int kq   = lane >> 4;

  // ---- phase 0: stage x (4ch x 4px per thread), swizzled bf16 tile ----
  {
    const int pq = t & 15;
    const int cg = (t >> 4) << 2;
    const int uu = cg >> 3;
    const int ho = ((cg >> 2) & 1) * 8;
    const float* s = xg + (size_t)b * (CCH * HW) + (size_t)cg * HW + pbase + pq * 4;
    f32x4 v0 = *(const f32x4*)(s);
    f32x4 v1 = *(const f32x4*)(s + HW);
    f32x4 v2 = *(const f32x4*)(s + 2 * HW);
    f32x4 v3 = *(const f32x4*)(s + 3 * HW);
    #pragma unroll
    for (int i = 0; i < 4; ++i) {
      const int px = pq * 4 + i;
      bf16x4 wv = { (__bf16)v0[i], (__bf16)v1[i], (__bf16)v2[i], (__bf16)v3[i] };
      *(bf16x4*)&xt[px * 128 + ((uu ^ (px & 7)) << 4) + ho] = wv;
    }
  }

  // ---- per-wave constant fragments (latency hides under staging) ----
  bf16x8 A[12];
  #pragma unroll
  for (int kk = 0; kk < 6; ++kk)
    #pragma unroll
    for (int sh = 0; sh < 2; ++sh)
      A[kk * 2 + sh] = *(const bf16x8*)(Pws + (size_t)((((2 * kk + sh) * 4 + w) * 64 + lane) << 3));

  bf16x8 W1a[2];
  {
    const float* wp = gw1 + lr * 64 + kq * 8;
    #pragma unroll
    for (int hh = 0; hh < 2; ++hh) {
      f32x4 lo = *(const f32x4*)(wp + hh * 32);
      f32x4 hi = *(const f32x4*)(wp + hh * 32 + 4);
      bf16x8 a;
      #pragma unroll
      for (int e = 0; e < 4; ++e) { a[e] = (__bf16)lo[e]; a[e + 4] = (__bf16)hi[e]; }
      W1a[hh] = a;
    }
  }
  const f32x4 gb1v  = *(const f32x4*)(gb1 + kq * 4);
  const f32x4 biasv = *(const f32x4*)(pbias + w * 16 + kq * 4);

  __syncthreads();

  // ---- phase A: gate pixel-group w only; share wm via LDS ----
  {
    const int col = w * 16 + lr;
    const bf16x8 B0 = *(const bf16x8*)&xt[col * 128 + ((kq       ^ (col & 7)) << 4)];
    const bf16x8 B1 = *(const bf16x8*)&xt[col * 128 + (((4 + kq) ^ (col & 7)) << 4)];

    f32x4 h = {0.f, 0.f, 0.f, 0.f};
    h = __builtin_amdgcn_mfma_f32_16x16x32_bf16(W1a[0], B0, h, 0, 0, 0);
    h = __builtin_amdgcn_mfma_f32_16x16x32_bf16(W1a[1], B1, h, 0, 0, 0);
    float hr[4];
    #pragma unroll
    for (int j = 0; j < 4; ++j) hr[j] = fmaxf(h[j] + gb1v[j], 0.f);

    float lg[6];
    #pragma unroll
    for (int kk = 0; kk < 6; ++kk) {
      const f32x4 w2 = *(const f32x4*)(gw2 + kk * 16 + kq * 4);
      lg[kk] = w2[0] * hr[0] + w2[1] * hr[1] + w2[2] * hr[2] + w2[3] * hr[3];
    }
    #pragma unroll
    for (int kk = 0; kk < 6; ++kk) lg[kk] += __shfl_xor(lg[kk], 16);
    #pragma unroll
    for (int kk = 0; kk < 6; ++kk) lg[kk] += __shfl_xor(lg[kk], 32);
    #pragma unroll
    for (int kk = 0; kk < 6; ++kk) lg[kk] += gb2[kk];

    float mx = fmaxf(fmaxf(fmaxf(lg[0], lg[1]), fmaxf(lg[2], lg[3])), fmaxf(lg[4], lg[5]));
    float ex[6], ssum = 0.f;
    #pragma unroll
    for (int kk = 0; kk < 6; ++kk) { ex[kk] = __expf(lg[kk] - mx); ssum += ex[kk]; }
    const float sinv = __builtin_amdgcn_rcpf(ssum);
    // softmax sums to 1 (+-3e-7): reference's renorm /(sum+1e-12) is a no-op
    if (kq == 0) {
      f32x4 o0 = { ex[0] * sinv, ex[1] * sinv, ex[2] * sinv, ex[3] * sinv };
      f32x4 o1 = { ex[4] * sinv, ex[5] * sinv, 0.f, 0.f };
      *(f32x4*)&wmld[col * 8 + 0] = o0;
      *(f32x4*)&wmld[col * 8 + 4] = o1;
    }
  }
  __syncthreads();

  // ---- phase B: main MFMA over all 4 pixel-groups -> obuf ----
  #pragma unroll
  for (int pg = 0; pg < 4; ++pg) {
    const int col = pg * 16 + lr;
    const bf16x8 B0 = *(const bf16x8*)&xt[col * 128 + ((kq       ^ (col & 7)) << 4)];
    const bf16x8 B1 = *(const bf16x8*)&xt[col * 128 + (((4 + kq) ^ (col & 7)) << 4)];
    const f32x4 wv0 = *(const f32x4*)&wmld[col * 8 + 0];
    const f32x4 wv1 = *(const f32x4*)&wmld[col * 8 + 4];
    const float wmv[6] = { wv0[0], wv0[1], wv0[2], wv0[3], wv1[0], wv1[1] };

    f32x4 facc = biasv;
    #pragma unroll
    for (int kk = 0; kk < 6; ++kk) {
      f32x4 y = {0.f, 0.f, 0.f, 0.f};
      y = __builtin_amdgcn_mfma_f32_16x16x32_bf16(A[2 * kk    ], B0, y, 0, 0, 0);
      y = __builtin_amdgcn_mfma_f32_16x16x32_bf16(A[2 * kk + 1], B1, y, 0, 0, 0);
      #pragma unroll
      for (int j = 0; j < 4; ++j) facc[j] += wmv[kk] * y[j];
    }
    #pragma unroll
    for (int j = 0; j < 4; ++j)
      obuf[(w * 16 + kq * 4 + j) * OSTR + col] = facc[j];
  }
  __syncthreads();

  // ---- epilogue: coalesced stores (4x dwordx4/wave, 256B runs per row) ----
  {
    float* outb = outg + (size_t)b * (OCH * HW) + pbase;
    const int er = lane >> 4;          // row sub-index 0..3
    const int ec = (lane & 15) * 4;    // px base (16 lanes x 16B = 256B/row)
    #pragma unroll
    for (int i = 0; i < 4; ++i) {
      const int o = w * 16 + er + 4 * i;
      f32x4 v = *(const f32x4*)&obuf[o * OSTR + ec];
      *(f32x4*)&outb[(size_t)o * HW + ec] = v;
    }
  }
}

extern "C" void kernel_launch(void* const* d_in, const int* in_sizes, int n_in,
                              void* d_out, int out_size, void* d_ws, size_t ws_size,
                              hipStream_t stream) {
  const float* x    = (const float*)d_in[0];
  const float* gw1  = (const float*)d_in[1];
  const float* gb1  = (const float*)d_in[2];
  const float* gw2  = (const float*)d_in[3];
  const float* gb2  = (const float*)d_in[4];
  const float* pw   = (const float*)d_in[5];
  const float* pb   = (const float*)d_in[6];
  const float* s53A = (const float*)d_in[7];
  const float* s53D = (const float*)d_in[8];
  const float* s97A = (const float*)d_in[9];
  const float* s97D = (const float*)d_in[10];
  __bf16* Pws = (__bf16*)d_ws;
  float* out = (float*)d_out;

  setup_P<<<48, 256, 0, stream>>>(pw, s53A, s53D, s97A, s97D, Pws);
  wavelet_main<<<2048, 256, 0, stream>>>(x, gw1, gb1, gw2, gb2, pb, Pws, out);
}

// Round 10
// 38.749 us; speedup vs baseline: 1.2105x; 1.0059x over previous
//
#include <hip/hip_runtime.h>
#include <hip/hip_bf16.h>
#include <math.h>

typedef __bf16 bf16x4 __attribute__((ext_vector_type(4)));
typedef __bf16 bf16x8 __attribute__((ext_vector_type(8)));
typedef float  f32x4  __attribute__((ext_vector_type(4)));

#define HW 16384   // 128*128
#define CCH 64
#define OCH 64

__device__ static const float FIRTAB[62] = {
  // db4 (8)
  -0.0105974017850021f, 0.0328830116668852f, 0.0308413818355607f, -0.1870348117188811f,
  -0.0279837694169839f, 0.6308807679295904f, 0.7148465705529155f, 0.2303778133088964f,
  // db6 (12)
  0.00107730108499558f, -0.00477725751101065f, -0.0005538422009938f, 0.03158203931748603f,
  0.02752286553030533f, -0.0975016055873225f, -0.12976686756709563f, 0.22626469396544f,
  0.3152503517092432f, -0.7511339080210959f, 0.4946238903984534f, 0.1115407433501095f,
  // sym6 (12)
  -0.007800708325034148f, 0.001767711864242804f, 0.04472490177066578f, -0.02106029251230056f,
  -0.0726375227866f, 0.3379294217282401f, 0.787641141030194f, 0.4910559419267466f,
  -0.048311742585632f, -0.1179901111484105f, 0.00349071208421747f, 0.01540410932702737f,
  // coif5 (30)
  -3.459977283621256e-05f, -7.098330313814114e-05f, 0.0004662169601128863f, 0.001117518770890601f,
  -0.002574517688750223f, -0.00900797613666158f, 0.015880544863615904f, 0.03455502757306163f,
  -0.08230192710688598f, -0.07179982161931202f, 0.42848347637761874f, 0.7937772226256206f,
  0.4051769024096169f, -0.06112339000267287f, -0.06577191128185562f, 0.023452696141836267f,
  0.007782596427325418f, -0.003793512864491014f, -0.0002606761356811993f, 0.000107502882505652f,
  1.10319778524429e-05f, -5.520763127949e-06f, -1.0682196848076e-06f, 5.236425333584e-07f,
  1.125098976034e-07f, -5.417490769329e-08f, -8.8631e-09f, 4.2921e-09f, 6.7e-10f, -3.2e-10f
};
__device__ static const int FIR_OFF[4] = {0, 8, 20, 32};
__device__ static const int FIR_LEN[4] = {8, 12, 12, 30};

// ---------------------------------------------------------------------------
// Kernel 1 (proven, unchanged): build P_k (64x64), fragment-linear bf16 out.
//   entry (k, o, c) -> Pout[(((s*4+mf)*64 + lane)*8 + e]
//   s = 2k + (c>>5), mf = o>>4, lane = (o&15) | (((c&31)>>3)<<4), e = c&7
// ---------------------------------------------------------------------------
__global__ __launch_bounds__(256) void setup_P(
    const float* __restrict__ pw,
    const float* __restrict__ s53A, const float* __restrict__ s53D,
    const float* __restrict__ s97A, const float* __restrict__ s97D,
    __bf16* __restrict__ Pout)
{
  __shared__ float matA[64][64];
  __shared__ float matD[64][64];
  __shared__ float tmpA[62][64];
  __shared__ float tmpD[62][64];

  const int k = blockIdx.x >> 3;
  const int q = blockIdx.x & 7;
  const int t = threadIdx.x;

  if (t < 64) {
    const int c = t;
    int Lin;
    if (k < 4) {
      const int L  = FIR_LEN[k];
      const int off = FIR_OFF[k];
      const int pad = (L - 1) / 2;
      const int pl  = pad - 1;
      float ss = 0.f;
      for (int l = 0; l < L; ++l) { float v = FIRTAB[off + l]; ss += v * v; }
      const float inv = 1.f / (sqrtf(ss) + 1e-12f);

      for (int i = 0; i < 62; ++i) { tmpA[i][c] = 0.f; tmpD[i][c] = 0.f; }
      for (int l = 0; l < L; ++l) {
        const float lov = FIRTAB[off + l] * inv;
        const float hiv = ((l & 1) ? -1.f : 1.f) * FIRTAB[off + L - 1 - l] * inv;
        const int base = pl - l;
        int i0 = c + base;
        if (i0 >= 0 && i0 < 62) { tmpA[i0][c] += lov; tmpD[i0][c] += hiv; }
        if (c > 0) {
          int i1 = -c + base;
          if (i1 >= 0 && i1 < 62) { tmpA[i1][c] += lov; tmpD[i1][c] += hiv; }
        }
        if (c < 63) {
          int i2 = 126 - c + base;
          if (i2 >= 0 && i2 < 62) { tmpA[i2][c] += lov; tmpD[i2][c] += hiv; }
        }
      }
      Lin = 62;
    } else {
      for (int i = 0; i < 32; ++i) {
        tmpA[i][c] = (c == 2 * i)     ? 1.f : 0.f;
        tmpD[i][c] = (c == 2 * i + 1) ? 1.f : 0.f;
      }
      float cf[4]; int nst;
      if (k == 4) { cf[0] = -0.5f; cf[1] = 0.25f; cf[2] = 0.f; cf[3] = 0.f; nst = 2; }
      else { cf[0] = -1.586134342f; cf[1] = -0.05298011854f;
             cf[2] = 0.8829110762f; cf[3] = 0.4435068522f; nst = 4; }
      for (int s = 0; s < nst; ++s) {
        if ((s & 1) == 0) {
          for (int i = 0; i < 32; ++i) {
            float a = tmpA[(i == 0) ? 1 : i - 1][c];
            float b2 = tmpA[(i == 31) ? 30 : i + 1][c];
            tmpD[i][c] += cf[s] * 0.5f * (a + b2);
          }
        } else {
          for (int i = 0; i < 32; ++i) {
            float a = tmpD[(i == 0) ? 1 : i - 1][c];
            float b2 = tmpD[(i == 31) ? 30 : i + 1][c];
            tmpA[i][c] += cf[s] * 0.5f * (a + b2);
          }
        }
      }
      Lin = 32;
    }
    float sA = 1.f, sD = 1.f;
    if (k == 4) { sA = s53A[0]; sD = s53D[0]; }
    if (k == 5) { sA = s97A[0]; sD = s97D[0]; }
    const float step = (float)Lin / 64.0f;
    for (int o = 0; o < 64; ++o) {
      float src = (o + 0.5f) * step - 0.5f;
      src = fmaxf(src, 0.f);
      int i0 = (int)floorf(src); if (i0 > Lin - 1) i0 = Lin - 1;
      int i1 = i0 + 1;           if (i1 > Lin - 1) i1 = Lin - 1;
      float w = src - (float)i0;
      matA[o][c] = sA * ((1.f - w) * tmpA[i0][c] + w * tmpA[i1][c]);
      matD[o][c] = sD * ((1.f - w) * tmpD[i0][c] + w * tmpD[i1][c]);
    }
  }
  __syncthreads();

  const int o  = q * 8 + (t & 7);
  const int c0 = (t >> 3) * 2;
  float acc[2] = {0.f, 0.f};
  for (int j = 0; j < 64; ++j) {
    const float wa = pw[o * 128 + j];
    const float wd = pw[o * 128 + 64 + j];
    #pragma unroll
    for (int cc = 0; cc < 2; ++cc)
      acc[cc] += wa * matA[j][c0 + cc] + wd * matD[j][c0 + cc];
  }
  #pragma unroll
  for (int cc = 0; cc < 2; ++cc) {
    const int c = c0 + cc;
    const int s = k * 2 + (c >> 5);
    const int mf = o >> 4;
    const int lane = (o & 15) | (((c & 31) >> 3) << 4);
    const int e = c & 7;
    Pout[(((s * 4 + mf) * 64 + lane) << 3) + e] = (__bf16)acc[cc];
  }
}

// ---------------------------------------------------------------------------
// Kernel 2: single-barrier, wave-self-staged main kernel.
//  1024 blocks x 256 threads; 128 px per block (4 generations, was 8).
//  Staging: wave w stages its OWN px range [w*32, w*32+32) across ALL 64
//  channels (8 f32x4/thread; 8x128B segments/instr) -> gate of the wave's
//  own 2 pixel-groups runs BEFORE any barrier (own-wave lgkmcnt suffices).
//  ONE __syncthreads, then phase B over all 8 pgs (identical math to R9).
//  Stores scattered (fire-and-forget; obuf dropped: +0.5us < barrier cost).
// ---------------------------------------------------------------------------
__global__ __launch_bounds__(256, 4) void wavelet_main(
    const float* __restrict__ xg,
    const float* __restrict__ gw1, const float* __restrict__ gb1,
    const float* __restrict__ gw2, const float* __restrict__ gb2,
    const float* __restrict__ pbias,
    const __bf16* __restrict__ Pws,
    float* __restrict__ outg)
{
  __shared__ __align__(16) unsigned char xt[128 * 128];  // 16 KB
  __shared__ __align__(16) float wmld[128 * 8];          //  4 KB

  const int t    = threadIdx.x;
  const int w    = t >> 6;
  const int lane = t & 63;
  const int lr   = lane & 15;
  const int kq   = lane >> 4;

  const int blk   = blockIdx.x;
  const int b     = blk >> 7;                 // 128 tiles per image
  const int pbase = (blk & 127) << 7;         // 128 px per tile

  // ---- staging: own-wave px quad x all 64 channels ----
  const int pq  = lane & 7;                   // px quad within wave's 32
  const int cg  = lane >> 3;                  // 8-channel group 0..7
  const int px0 = w * 32 + pq * 4;

  const float* s = xg + (size_t)b * (CCH * HW) + (size_t)(cg * 8) * HW + pbase + px0;
  f32x4 v[8];
  #pragma unroll
  for (int r = 0; r < 8; ++r) v[r] = *(const f32x4*)(s + (size_t)r * HW);

  // ---- per-wave constants (latency hides under staging loads) ----
  bf16x8 A[12];
  #pragma unroll
  for (int kk = 0; kk < 6; ++kk)
    #pragma unroll
    for (int sh = 0; sh < 2; ++sh)
      A[kk * 2 + sh] = *(const bf16x8*)(Pws + (size_t)((((2 * kk + sh) * 4 + w) * 64 + lane) << 3));

  bf16x8 W1a[2];
  {
    const float* wp = gw1 + lr * 64 + kq * 8;
    #pragma unroll
    for (int hh = 0; hh < 2; ++hh) {
      f32x4 lo = *(const f32x4*)(wp + hh * 32);
      f32x4 hi = *(const f32x4*)(wp + hh * 32 + 4);
      bf16x8 a;
      #pragma unroll
      for (int e = 0; e < 4; ++e) { a[e] = (__bf16)lo[e]; a[e + 4] = (__bf16)hi[e]; }
      W1a[hh] = a;
    }
  }
  const f32x4 gb1v  = *(const f32x4*)(gb1 + kq * 4);
  const f32x4 biasv = *(const f32x4*)(pbias + w * 16 + kq * 4);

  // ---- write own 8ch x 4px into swizzled bf16 tile ----
  #pragma unroll
  for (int i = 0; i < 4; ++i) {
    const int px = px0 + i;
    bf16x8 wv;
    #pragma unroll
    for (int e = 0; e < 8; ++e) wv[e] = (__bf16)v[e][i];
    *(bf16x8*)&xt[px * 128 + ((cg ^ (px & 7)) << 4)] = wv;
  }

  // ---- phase A (pre-barrier): gate the wave's OWN two pixel-groups ----
  #pragma unroll
  for (int pp = 0; pp < 2; ++pp) {
    const int col = (2 * w + pp) * 16 + lr;   // in [w*32, w*32+32): own-staged
    const bf16x8 B0 = *(const bf16x8*)&xt[col * 128 + ((kq       ^ (col & 7)) << 4)];
    const bf16x8 B1 = *(const bf16x8*)&xt[col * 128 + (((4 + kq) ^ (col & 7)) << 4)];

    f32x4 h = {0.f, 0.f, 0.f, 0.f};
    h = __builtin_amdgcn_mfma_f32_16x16x32_bf16(W1a[0], B0, h, 0, 0, 0);
    h = __builtin_amdgcn_mfma_f32_16x16x32_bf16(W1a[1], B1, h, 0, 0, 0);
    float hr[4];
    #pragma unroll
    for (int j = 0; j < 4; ++j) hr[j] = fmaxf(h[j] + gb1v[j], 0.f);

    float lg[6];
    #pragma unroll
    for (int kk = 0; kk < 6; ++kk) {
      const f32x4 w2 = *(const f32x4*)(gw2 + kk * 16 + kq * 4);
      lg[kk] = w2[0] * hr[0] + w2[1] * hr[1] + w2[2] * hr[2] + w2[3] * hr[3];
    }
    #pragma unroll
    for (int kk = 0; kk < 6; ++kk) lg[kk] += __shfl_xor(lg[kk], 16);
    #pragma unroll
    for (int kk = 0; kk < 6; ++kk) lg[kk] += __shfl_xor(lg[kk], 32);
    #pragma unroll
    for (int kk = 0; kk < 6; ++kk) lg[kk] += gb2[kk];

    float mx = fmaxf(fmaxf(fmaxf(lg[0], lg[1]), fmaxf(lg[2], lg[3])), fmaxf(lg[4], lg[5]));
    float ex[6], ssum = 0.f;
    #pragma unroll
    for (int kk = 0; kk < 6; ++kk) { ex[kk] = __expf(lg[kk] - mx); ssum += ex[kk]; }
    const float sinv = __builtin_amdgcn_rcpf(ssum);
    // softmax sums to 1 (+-3e-7): reference's renorm /(sum+1e-12) is a no-op
    if (kq == 0) {
      f32x4 o0 = { ex[0] * sinv, ex[1] * sinv, ex[2] * sinv, ex[3] * sinv };
      f32x4 o1 = { ex[4] * sinv, ex[5] * sinv, 0.f, 0.f };
      *(f32x4*)&wmld[col * 8 + 0] = o0;
      *(f32x4*)&wmld[col * 8 + 4] = o1;
    }
  }
  __syncthreads();   // the ONLY barrier

  // ---- phase B: main MFMA over all 8 pixel-groups, scattered stores ----
  float* outb = outg + (size_t)b * (OCH * HW) + pbase;

  #pragma unroll
  for (int pg = 0; pg < 8; ++pg) {
    const int col = pg * 16 + lr;
    const bf16x8 B0 = *(const bf16x8*)&xt[col * 128 + ((kq       ^ (col & 7)) << 4)];
    const bf16x8 B1 = *(const bf16x8*)&xt[col * 128 + (((4 + kq) ^ (col & 7)) << 4)];
    const f32x4 wv0 = *(const f32x4*)&wmld[col * 8 + 0];
    const f32x4 wv1 = *(const f32x4*)&wmld[col * 8 + 4];
    const float wmv[6] = { wv0[0], wv0[1], wv0[2], wv0[3], wv1[0], wv1[1] };

    f32x4 facc = biasv;
    #pragma unroll
    for (int kk = 0; kk < 6; ++kk) {
      f32x4 y = {0.f, 0.f, 0.f, 0.f};
      y = __builtin_amdgcn_mfma_f32_16x16x32_bf16(A[2 * kk    ], B0, y, 0, 0, 0);
      y = __builtin_amdgcn_mfma_f32_16x16x32_bf16(A[2 * kk + 1], B1, y, 0, 0, 0);
      #pragma unroll
      for (int j = 0; j < 4; ++j) facc[j] += wmv[kk] * y[j];
    }
    #pragma unroll
    for (int j = 0; j < 4; ++j) {
      const int o = w * 16 + kq * 4 + j;
      outb[(size_t)o * HW + col] = facc[j];
    }
  }
}

extern "C" void kernel_launch(void* const* d_in, const int* in_sizes, int n_in,
                              void* d_out, int out_size, void* d_ws, size_t ws_size,
                              hipStream_t stream) {
  const float* x    = (const float*)d_in[0];
  const float* gw1  = (const float*)d_in[1];
  const float* gb1  = (const float*)d_in[2];
  const float* gw2  = (const float*)d_in[3];
  const float* gb2  = (const float*)d_in[4];
  const float* pw   = (const float*)d_in[5];
  const float* pb   = (const float*)d_in[6];
  const float* s53A = (const float*)d_in[7];
  const float* s53D = (const float*)d_in[8];
  const float* s97A = (const float*)d_in[9];
  const float* s97D = (const float*)d_in[10];
  __bf16* Pws = (__bf16*)d_ws;
  float* out = (float*)d_out;

  setup_P<<<48, 256, 0, stream>>>(pw, s53A, s53D, s97A, s97D, Pws);
  wavelet_main<<<1024, 256, 0, stream>>>(x, gw1, gb1, gw2, gb2, pb, Pws, out);
}

// Round 11
// 38.735 us; speedup vs baseline: 1.2110x; 1.0004x over previous
//
#include <hip/hip_runtime.h>
#include <hip/hip_bf16.h>
#include <math.h>

typedef __bf16 bf16x4 __attribute__((ext_vector_type(4)));
typedef __bf16 bf16x8 __attribute__((ext_vector_type(8)));
typedef float  f32x4  __attribute__((ext_vector_type(4)));

#define HW 16384   // 128*128
#define CCH 64
#define OCH 64

__device__ static const float FIRTAB[62] = {
  // db4 (8)
  -0.0105974017850021f, 0.0328830116668852f, 0.0308413818355607f, -0.1870348117188811f,
  -0.0279837694169839f, 0.6308807679295904f, 0.7148465705529155f, 0.2303778133088964f,
  // db6 (12)
  0.00107730108499558f, -0.00477725751101065f, -0.0005538422009938f, 0.03158203931748603f,
  0.02752286553030533f, -0.0975016055873225f, -0.12976686756709563f, 0.22626469396544f,
  0.3152503517092432f, -0.7511339080210959f, 0.4946238903984534f, 0.1115407433501095f,
  // sym6 (12)
  -0.007800708325034148f, 0.001767711864242804f, 0.04472490177066578f, -0.02106029251230056f,
  -0.0726375227866f, 0.3379294217282401f, 0.787641141030194f, 0.4910559419267466f,
  -0.048311742585632f, -0.1179901111484105f, 0.00349071208421747f, 0.01540410932702737f,
  // coif5 (30)
  -3.459977283621256e-05f, -7.098330313814114e-05f, 0.0004662169601128863f, 0.001117518770890601f,
  -0.002574517688750223f, -0.00900797613666158f, 0.015880544863615904f, 0.03455502757306163f,
  -0.08230192710688598f, -0.07179982161931202f, 0.42848347637761874f, 0.7937772226256206f,
  0.4051769024096169f, -0.06112339000267287f, -0.06577191128185562f, 0.023452696141836267f,
  0.007782596427325418f, -0.003793512864491014f, -0.0002606761356811993f, 0.000107502882505652f,
  1.10319778524429e-05f, -5.520763127949e-06f, -1.0682196848076e-06f, 5.236425333584e-07f,
  1.125098976034e-07f, -5.417490769329e-08f, -8.8631e-09f, 4.2921e-09f, 6.7e-10f, -3.2e-10f
};
__device__ static const int FIR_OFF[4] = {0, 8, 20, 32};
__device__ static const int FIR_LEN[4] = {8, 12, 12, 30};

// ---------------------------------------------------------------------------
// Kernel 1 (proven, unchanged): build P_k (64x64), fragment-linear bf16 out.
//   entry (k, o, c) -> Pout[(((s*4+mf)*64 + lane)*8 + e]
//   s = 2k + (c>>5), mf = o>>4, lane = (o&15) | (((c&31)>>3)<<4), e = c&7
// ---------------------------------------------------------------------------
__global__ __launch_bounds__(256) void setup_P(
    const float* __restrict__ pw,
    const float* __restrict__ s53A, const float* __restrict__ s53D,
    const float* __restrict__ s97A, const float* __restrict__ s97D,
    __bf16* __restrict__ Pout)
{
  __shared__ float matA[64][64];
  __shared__ float matD[64][64];
  __shared__ float tmpA[62][64];
  __shared__ float tmpD[62][64];

  const int k = blockIdx.x >> 3;
  const int q = blockIdx.x & 7;
  const int t = threadIdx.x;

  if (t < 64) {
    const int c = t;
    int Lin;
    if (k < 4) {
      const int L  = FIR_LEN[k];
      const int off = FIR_OFF[k];
      const int pad = (L - 1) / 2;
      const int pl  = pad - 1;
      float ss = 0.f;
      for (int l = 0; l < L; ++l) { float v = FIRTAB[off + l]; ss += v * v; }
      const float inv = 1.f / (sqrtf(ss) + 1e-12f);

      for (int i = 0; i < 62; ++i) { tmpA[i][c] = 0.f; tmpD[i][c] = 0.f; }
      for (int l = 0; l < L; ++l) {
        const float lov = FIRTAB[off + l] * inv;
        const float hiv = ((l & 1) ? -1.f : 1.f) * FIRTAB[off + L - 1 - l] * inv;
        const int base = pl - l;
        int i0 = c + base;
        if (i0 >= 0 && i0 < 62) { tmpA[i0][c] += lov; tmpD[i0][c] += hiv; }
        if (c > 0) {
          int i1 = -c + base;
          if (i1 >= 0 && i1 < 62) { tmpA[i1][c] += lov; tmpD[i1][c] += hiv; }
        }
        if (c < 63) {
          int i2 = 126 - c + base;
          if (i2 >= 0 && i2 < 62) { tmpA[i2][c] += lov; tmpD[i2][c] += hiv; }
        }
      }
      Lin = 62;
    } else {
      for (int i = 0; i < 32; ++i) {
        tmpA[i][c] = (c == 2 * i)     ? 1.f : 0.f;
        tmpD[i][c] = (c == 2 * i + 1) ? 1.f : 0.f;
      }
      float cf[4]; int nst;
      if (k == 4) { cf[0] = -0.5f; cf[1] = 0.25f; cf[2] = 0.f; cf[3] = 0.f; nst = 2; }
      else { cf[0] = -1.586134342f; cf[1] = -0.05298011854f;
             cf[2] = 0.8829110762f; cf[3] = 0.4435068522f; nst = 4; }
      for (int s = 0; s < nst; ++s) {
        if ((s & 1) == 0) {
          for (int i = 0; i < 32; ++i) {
            float a = tmpA[(i == 0) ? 1 : i - 1][c];
            float b2 = tmpA[(i == 31) ? 30 : i + 1][c];
            tmpD[i][c] += cf[s] * 0.5f * (a + b2);
          }
        } else {
          for (int i = 0; i < 32; ++i) {
            float a = tmpD[(i == 0) ? 1 : i - 1][c];
            float b2 = tmpD[(i == 31) ? 30 : i + 1][c];
            tmpA[i][c] += cf[s] * 0.5f * (a + b2);
          }
        }
      }
      Lin = 32;
    }
    float sA = 1.f, sD = 1.f;
    if (k == 4) { sA = s53A[0]; sD = s53D[0]; }
    if (k == 5) { sA = s97A[0]; sD = s97D[0]; }
    const float step = (float)Lin / 64.0f;
    for (int o = 0; o < 64; ++o) {
      float src = (o + 0.5f) * step - 0.5f;
      src = fmaxf(src, 0.f);
      int i0 = (int)floorf(src); if (i0 > Lin - 1) i0 = Lin - 1;
      int i1 = i0 + 1;           if (i1 > Lin - 1) i1 = Lin - 1;
      float w = src - (float)i0;
      matA[o][c] = sA * ((1.f - w) * tmpA[i0][c] + w * tmpA[i1][c]);
      matD[o][c] = sD * ((1.f - w) * tmpD[i0][c] + w * tmpD[i1][c]);
    }
  }
  __syncthreads();

  const int o  = q * 8 + (t & 7);
  const int c0 = (t >> 3) * 2;
  float acc[2] = {0.f, 0.f};
  for (int j = 0; j < 64; ++j) {
    const float wa = pw[o * 128 + j];
    const float wd = pw[o * 128 + 64 + j];
    #pragma unroll
    for (int cc = 0; cc < 2; ++cc)
      acc[cc] += wa * matA[j][c0 + cc] + wd * matD[j][c0 + cc];
  }
  #pragma unroll
  for (int cc = 0; cc < 2; ++cc) {
    const int c = c0 + cc;
    const int s = k * 2 + (c >> 5);
    const int mf = o >> 4;
    const int lane = (o & 15) | (((c & 31) >> 3) << 4);
    const int e = c & 7;
    Pout[(((s * 4 + mf) * 64 + lane) << 3) + e] = (__bf16)acc[cc];
  }
}

// ---------------------------------------------------------------------------
// Kernel 2: R10 verbatim EXCEPT __launch_bounds__(256, 2) — raise VGPR cap
// to ~256 so all ~24 global loads (staging 32 VGPR + A-frags 48 + W1 8)
// have live landing registers and stay in flight simultaneously.
// Theory: the (256,4)=128-VGPR cap forced the allocator to serialize the
// load burst into load->wait->consume chunks (R2's measured failure mode),
// which explains the structure-invariant ~39 us. Occupancy 2 blocks/CU
// (8 waves, 32 KB in flight > 22 KB Little's-law requirement).
// ---------------------------------------------------------------------------
__global__ __launch_bounds__(256, 2) void wavelet_main(
    const float* __restrict__ xg,
    const float* __restrict__ gw1, const float* __restrict__ gb1,
    const float* __restrict__ gw2, const float* __restrict__ gb2,
    const float* __restrict__ pbias,
    const __bf16* __restrict__ Pws,
    float* __restrict__ outg)
{
  __shared__ __align__(16) unsigned char xt[128 * 128];  // 16 KB
  __shared__ __align__(16) float wmld[128 * 8];          //  4 KB

  const int t    = threadIdx.x;
  const int w    = t >> 6;
  const int lane = t & 63;
  const int lr   = lane & 15;
  const int kq   = lane >> 4;

  const int blk   = blockIdx.x;
  const int b     = blk >> 7;                 // 128 tiles per image
  const int pbase = (blk & 127) << 7;         // 128 px per tile

  // ---- staging: own-wave px quad x all 64 channels ----
  const int pq  = lane & 7;                   // px quad within wave's 32
  const int cg  = lane >> 3;                  // 8-channel group 0..7
  const int px0 = w * 32 + pq * 4;

  const float* s = xg + (size_t)b * (CCH * HW) + (size_t)(cg * 8) * HW + pbase + px0;
  f32x4 v[8];
  #pragma unroll
  for (int r = 0; r < 8; ++r) v[r] = *(const f32x4*)(s + (size_t)r * HW);

  // ---- per-wave constants (latency hides under staging loads) ----
  bf16x8 A[12];
  #pragma unroll
  for (int kk = 0; kk < 6; ++kk)
    #pragma unroll
    for (int sh = 0; sh < 2; ++sh)
      A[kk * 2 + sh] = *(const bf16x8*)(Pws + (size_t)((((2 * kk + sh) * 4 + w) * 64 + lane) << 3));

  bf16x8 W1a[2];
  {
    const float* wp = gw1 + lr * 64 + kq * 8;
    #pragma unroll
    for (int hh = 0; hh < 2; ++hh) {
      f32x4 lo = *(const f32x4*)(wp + hh * 32);
      f32x4 hi = *(const f32x4*)(wp + hh * 32 + 4);
      bf16x8 a;
      #pragma unroll
      for (int e = 0; e < 4; ++e) { a[e] = (__bf16)lo[e]; a[e + 4] = (__bf16)hi[e]; }
      W1a[hh] = a;
    }
  }
  const f32x4 gb1v  = *(const f32x4*)(gb1 + kq * 4);
  const f32x4 biasv = *(const f32x4*)(pbias + w * 16 + kq * 4);

  // ---- write own 8ch x 4px into swizzled bf16 tile ----
  #pragma unroll
  for (int i = 0; i < 4; ++i) {
    const int px = px0 + i;
    bf16x8 wv;
    #pragma unroll
    for (int e = 0; e < 8; ++e) wv[e] = (__bf16)v[e][i];
    *(bf16x8*)&xt[px * 128 + ((cg ^ (px & 7)) << 4)] = wv;
  }

  // ---- phase A (pre-barrier): gate the wave's OWN two pixel-groups ----
  #pragma unroll
  for (int pp = 0; pp < 2; ++pp) {
    const int col = (2 * w + pp) * 16 + lr;   // in [w*32, w*32+32): own-staged
    const bf16x8 B0 = *(const bf16x8*)&xt[col * 128 + ((kq       ^ (col & 7)) << 4)];
    const bf16x8 B1 = *(const bf16x8*)&xt[col * 128 + (((4 + kq) ^ (col & 7)) << 4)];

    f32x4 h = {0.f, 0.f, 0.f, 0.f};
    h = __builtin_amdgcn_mfma_f32_16x16x32_bf16(W1a[0], B0, h, 0, 0, 0);
    h = __builtin_amdgcn_mfma_f32_16x16x32_bf16(W1a[1], B1, h, 0, 0, 0);
    float hr[4];
    #pragma unroll
    for (int j = 0; j < 4; ++j) hr[j] = fmaxf(h[j] + gb1v[j], 0.f);

    float lg[6];
    #pragma unroll
    for (int kk = 0; kk < 6; ++kk) {
      const f32x4 w2 = *(const f32x4*)(gw2 + kk * 16 + kq * 4);
      lg[kk] = w2[0] * hr[0] + w2[1] * hr[1] + w2[2] * hr[2] + w2[3] * hr[3];
    }
    #pragma unroll
    for (int kk = 0; kk < 6; ++kk) lg[kk] += __shfl_xor(lg[kk], 16);
    #pragma unroll
    for (int kk = 0; kk < 6; ++kk) lg[kk] += __shfl_xor(lg[kk], 32);
    #pragma unroll
    for (int kk = 0; kk < 6; ++kk) lg[kk] += gb2[kk];

    float mx = fmaxf(fmaxf(fmaxf(lg[0], lg[1]), fmaxf(lg[2], lg[3])), fmaxf(lg[4], lg[5]));
    float ex[6], ssum = 0.f;
    #pragma unroll
    for (int kk = 0; kk < 6; ++kk) { ex[kk] = __expf(lg[kk] - mx); ssum += ex[kk]; }
    const float sinv = __builtin_amdgcn_rcpf(ssum);
    // softmax sums to 1 (+-3e-7): reference's renorm /(sum+1e-12) is a no-op
    if (kq == 0) {
      f32x4 o0 = { ex[0] * sinv, ex[1] * sinv, ex[2] * sinv, ex[3] * sinv };
      f32x4 o1 = { ex[4] * sinv, ex[5] * sinv, 0.f, 0.f };
      *(f32x4*)&wmld[col * 8 + 0] = o0;
      *(f32x4*)&wmld[col * 8 + 4] = o1;
    }
  }
  __syncthreads();   // the ONLY barrier

  // ---- phase B: main MFMA over all 8 pixel-groups, scattered stores ----
  float* outb = outg + (size_t)b * (OCH * HW) + pbase;

  #pragma unroll
  for (int pg = 0; pg < 8; ++pg) {
    const int col = pg * 16 + lr;
    const bf16x8 B0 = *(const bf16x8*)&xt[col * 128 + ((kq       ^ (col & 7)) << 4)];
    const bf16x8 B1 = *(const bf16x8*)&xt[col * 128 + (((4 + kq) ^ (col & 7)) << 4)];
    const f32x4 wv0 = *(const f32x4*)&wmld[col * 8 + 0];
    const f32x4 wv1 = *(const f32x4*)&wmld[col * 8 + 4];
    const float wmv[6] = { wv0[0], wv0[1], wv0[2], wv0[3], wv1[0], wv1[1] };

    f32x4 facc = biasv;
    #pragma unroll
    for (int kk = 0; kk < 6; ++kk) {
      f32x4 y = {0.f, 0.f, 0.f, 0.f};
      y = __builtin_amdgcn_mfma_f32_16x16x32_bf16(A[2 * kk    ], B0, y, 0, 0, 0);
      y = __builtin_amdgcn_mfma_f32_16x16x32_bf16(A[2 * kk + 1], B1, y, 0, 0, 0);
      #pragma unroll
      for (int j = 0; j < 4; ++j) facc[j] += wmv[kk] * y[j];
    }
    #pragma unroll
    for (int j = 0; j < 4; ++j) {
      const int o = w * 16 + kq * 4 + j;
      outb[(size_t)o * HW + col] = facc[j];
    }
  }
}

extern "C" void kernel_launch(void* const* d_in, const int* in_sizes, int n_in,
                              void* d_out, int out_size, void* d_ws, size_t ws_size,
                              hipStream_t stream) {
  const float* x    = (const float*)d_in[0];
  const float* gw1  = (const float*)d_in[1];
  const float* gb1  = (const float*)d_in[2];
  const float* gw2  = (const float*)d_in[3];
  const float* gb2  = (const float*)d_in[4];
  const float* pw   = (const float*)d_in[5];
  const float* pb   = (const float*)d_in[6];
  const float* s53A = (const float*)d_in[7];
  const float* s53D = (const float*)d_in[8];
  const float* s97A = (const float*)d_in[9];
  const float* s97D = (const float*)d_in[10];
  __bf16* Pws = (__bf16*)d_ws;
  float* out = (float*)d_out;

  setup_P<<<48, 256, 0, stream>>>(pw, s53A, s53D, s97A, s97D, Pws);
  wavelet_main<<<1024, 256, 0, stream>>>(x, gw1, gb1, gw2, gb2, pb, Pws, out);
}